// Round 10
// baseline (5810.684 us; speedup 1.0000x reference)
//
#include <hip/hip_runtime.h>
#include <stdint.h>

#define B_ 512
#define T_ 512

typedef __attribute__((ext_vector_type(8))) __bf16 bf16x8;
typedef __attribute__((ext_vector_type(4))) float f32x4;
typedef __attribute__((ext_vector_type(8))) unsigned short u16x8;

// d_ws layout (bytes):
//   [0)        packed bf16 weights (pack_w), 958464 u16 = 1916928 B
//   [N0OFF)    R0 ring: 16 groups x 4 slots x 32 rows x 240 cols u16 = 983040 B
//   [N1OFF)    R1 ring: 16 x 4 x 32 x 160 u16 = 655360 B
//   [N2OFF)    R2 ring: 16 x 4 x 32 x 128 u16 = 524288 B
//   [FLOFF)    flags: 16 groups x 9 stages x 16 ints (64B spaced) = 9216 B
#define N0OFF 1916928u
#define N1OFF 2899968u
#define N2OFF 3555328u
#define FLOFF 4079616u

// 9 stages x 8 pair-blocks = 72 blocks. Block (s,p) serves groups gA=p, gB=p+8
// (two independent 32-row RNN pipelines), interleaved A-phase/B-phase per step
// so each group's flag-publish/poll latency hides under the other group's work.
// Weights live in LDS once (shared by both groups). Rings depth-4, sc1 data
// stores (LLC write-through), relaxed flags after vmcnt drain; consumer does
// relaxed polls + one ACQUIRE per phase.
constexpr int L_[9]   = {0,0,0, 1,1,1,1, 2,2};
constexpr int NT0_[9] = {0,5,10, 0,3,6,8, 0,4};
constexpr int NT_[9]  = {5,5,5, 3,3,2,2, 4,4};
constexpr int KT_[3]  = {8,12,9};
constexpr int NPT_[3] = {15,10,8};
constexpr int SC_[3]  = {231,153,128};
constexpr int RS_[3]  = {264,392,296};
constexpr int CB_[3]  = {0,231,384};
constexpr int RC_[3]  = {240,160,128};
constexpr unsigned WOFF_[3] = {0u,184320u,368640u};
// wait lists: flag index (stage within group) + lag (need flag >= t+lag)
constexpr int WN_[9] = {6,6,6, 8,8,8,8, 5,5};
constexpr int WF_[9][8] = {
  {1,2,3,4,5,6,0,0},{0,2,3,4,5,6,0,0},{0,1,3,4,5,6,0,0},
  {0,1,2,4,5,6,7,8},{0,1,2,3,5,6,7,8},{0,1,2,3,4,6,7,8},{0,1,2,3,4,5,7,8},
  {3,4,5,6,8,0,0,0},{3,4,5,6,7,0,0,0}};
constexpr int WL_[9][8] = {
  {1,1,-2,-2,-2,-2,0,0},{1,1,-2,-2,-2,-2,0,0},{1,1,-2,-2,-2,-2,0,0},
  {2,2,2,1,1,1,-2,-2},{2,2,2,1,1,1,-2,-2},{2,2,2,1,1,1,-2,-2},{2,2,2,1,1,1,-2,-2},
  {2,2,2,2,1,0,0,0},{2,2,2,2,1,0,0,0}};

static __device__ __forceinline__ uint16_t bfbits(float f){
  __bf16 h = (__bf16)f; return __builtin_bit_cast(uint16_t, h);
}
static __device__ __forceinline__ float sigm_f(float x){
  return __builtin_amdgcn_rcpf(1.0f + __builtin_amdgcn_exp2f(-1.4426950408889634f*x));
}
static __device__ __forceinline__ float tanh_f(float x){
  return 2.0f*__builtin_amdgcn_rcpf(1.0f + __builtin_amdgcn_exp2f(-2.8853900817779268f*x)) - 1.0f;
}
static __device__ __forceinline__ uint32_t ldg32(const uint32_t* p){
  return __hip_atomic_load(p, __ATOMIC_RELAXED, __HIP_MEMORY_SCOPE_AGENT);
}
static __device__ __forceinline__ uint16_t ldg16(const uint16_t* p){
  return __hip_atomic_load(p, __ATOMIC_RELAXED, __HIP_MEMORY_SCOPE_AGENT);
}
static __device__ __forceinline__ void stg16(uint16_t* p, uint16_t v){
  __hip_atomic_store(p, v, __ATOMIC_RELAXED, __HIP_MEMORY_SCOPE_AGENT);  // sc1
}
#define DRAIN() asm volatile("s_waitcnt vmcnt(0)" ::: "memory")

__global__ void zero_flags(uint8_t* wsb){
  int i = blockIdx.x*512 + threadIdx.x;
  if (i < 2304) ((int*)(wsb + FLOFF))[i] = 0;
}

__global__ void pack_w(const float* __restrict__ W1, const float* __restrict__ W2,
                       const float* __restrict__ Wa, const float* __restrict__ Wb,
                       const float* __restrict__ Msk, uint16_t* __restrict__ dst,
                       int NPT, int KT, int S, int C)
{
  int c = blockIdx.x * 256 + threadIdx.x;
  int chunks = 3 * NPT * KT * 64;
  if (c >= chunks) return;
  int perN = KT * 64;
  int n3 = c / perN, r = c % perN;
  int kt = r >> 6, lane = r & 63;
  int m = n3 / NPT, nt = n3 % NPT;
  int j = nt * 16 + (lane & 15);
  int kb = kt * 32 + (lane >> 4) * 8;
  u16x8 o;
  #pragma unroll
  for (int i = 0; i < 8; ++i){
    int k = kb + i;
    float v = 0.f;
    if (j < S && k < C){
      size_t idx = (size_t)j * C + k;
      if (m == 0)      v = W1[idx] * Msk[idx];
      else if (m == 1) v = W2[idx] * Msk[idx];
      else             v = Wa[idx] + Wb[idx];
    }
    o[i] = bfbits(v);
  }
  *(u16x8*)(dst + (size_t)c * 8) = o;
}

template<int SID>
__device__ __forceinline__ void stage_run(
    int gA, int gB, int tid,
    const float* __restrict__ elapsed, const float* __restrict__ enc,
    const float* __restrict__ bp1, const float* __restrict__ bp2,
    const float* __restrict__ bpa, const float* __restrict__ bpb,
    const uint16_t* __restrict__ Wp, uint8_t* __restrict__ wsb,
    float* __restrict__ out, uint16_t* Wl, uint16_t* XA)
{
  constexpr int LAYER = L_[SID];
  constexpr int NT0 = NT0_[SID], NT = NT_[SID];
  constexpr int KT = KT_[LAYER], NPT = NPT_[LAYER];
  constexpr int SCOL = SC_[LAYER], RS = RS_[LAYER];
  constexpr int CBASE = CB_[LAYER], RC = RC_[LAYER];

  const int wave = tid >> 6, lane = tid & 63, llo = lane & 15, lhi = lane >> 4;
  const int rowg = tid >> 4, cg = tid & 15;       // 32 rows x 16 threads
  const size_t OH = (size_t)B_ * T_ * 128;

  uint16_t* RB0 = (uint16_t*)(wsb + N0OFF);
  uint16_t* RB1 = (uint16_t*)(wsb + N1OFF);
  uint16_t* RB2 = (uint16_t*)(wsb + N2OFF);
  int* FLB = (int*)(wsb + FLOFF);

  uint16_t* R0A = RB0 + (size_t)gA*(4*32*240);
  uint16_t* R1A = RB1 + (size_t)gA*(4*32*160);
  uint16_t* R2A = RB2 + (size_t)gA*(4*32*128);
  uint16_t* R0B = RB0 + (size_t)gB*(4*32*240);
  uint16_t* R1B = RB1 + (size_t)gB*(4*32*160);
  uint16_t* R2B = RB2 + (size_t)gB*(4*32*128);
  int* FLGA = FLB + gA*(9*16);
  int* FLGB = FLB + gB*(9*16);
  uint16_t* RNGA = (LAYER==0) ? R0A : (LAYER==1) ? R1A : R2A;
  uint16_t* RNGB = (LAYER==0) ? R0B : (LAYER==1) ? R1B : R2B;

  // ---- weights: global (packed) -> LDS, once; shared by both groups ----
  {
    const u16x8* Wp8 = (const u16x8*)(Wp + WOFF_[LAYER]);
    u16x8* Wl8 = (u16x8*)Wl;
    constexpr int CHUNKS = 3 * NT * KT * 64;
    for (int c = tid; c < CHUNKS; c += 512){
      int m = c / (NT*KT*64), r = c - m*(NT*KT*64);
      int tl = r / (KT*64),  r2 = r - tl*(KT*64);
      Wl8[c] = Wp8[(size_t)((m*NPT + NT0 + tl)*KT*64) + r2];
    }
  }
  // ---- XA zero (pad columns must stay 0; reused by both groups) ----
  for (int i = tid; i < 32*RS; i += 512) XA[i] = 0;

  // ---- biases -> registers (shared) ----
  float bs0 = 0.f, bs1 = 0.f, bs2 = 0.f;
  if (wave < NT){
    const int j = (NT0 + wave)*16 + llo;
    if (j < SCOL){ bs0 = bp1[j]; bs1 = bp2[j]; bs2 = bpa[j] + bpb[j]; }
  }

  // ---- init state (-1) into ring slot 3 for both groups ----
  #pragma unroll
  for (int gi = 0; gi < 2; ++gi){
    const int b0 = (gi ? gB : gA) * 32;
    uint16_t* RNG = gi ? RNGB : RNGA;
    for (int idx = tid; idx < 32*NT*16; idx += 512){
      int row = idx / (NT*16), jl = idx % (NT*16);
      int j = NT0*16 + jl;
      float v = 0.f;
      if (j < SCOL){
        if constexpr (LAYER == 0) v = enc[(size_t)(b0+row)*512 + j];
        else if constexpr (LAYER == 1) v = enc[(size_t)(b0+row)*512 + 231 + j];
        else v = enc[(size_t)(b0+row)*512 + 384 + j];
      }
      stg16(&RNG[(size_t)(3*32 + row)*RC + j], bfbits(v));
    }
  }
  DRAIN();
  __syncthreads();
  if (tid == 0){
    __threadfence();   // once: publish init
    __hip_atomic_store(&FLGA[SID*16], 1, __ATOMIC_RELEASE, __HIP_MEMORY_SCOPE_AGENT);
    __hip_atomic_store(&FLGB[SID*16], 1, __ATOMIC_RELEASE, __HIP_MEMORY_SCOPE_AGENT);
  }

  // ================= one phase (one group, one step) =================
  auto phase = [&](int* FLG, uint16_t* R0g, uint16_t* R1g, uint16_t* R2g,
                   uint16_t* RNGg, int b0, int t){
    // wait: batched relaxed polls + one acquire
    if (tid == 0){
      int spin = 0;
      for (;;){
        bool ok = true;
        #pragma unroll
        for (int i = 0; i < WN_[SID]; ++i){
          int v = __hip_atomic_load(&FLG[WF_[SID][i]*16], __ATOMIC_RELAXED,
                                    __HIP_MEMORY_SCOPE_AGENT);
          ok &= (v >= t + WL_[SID][i]);
        }
        if (ok) break;
        __builtin_amdgcn_s_sleep(2);
        if ((++spin & 15) == 0)
          (void)__hip_atomic_load(&FLG[WF_[SID][0]*16], __ATOMIC_ACQUIRE,
                                  __HIP_MEMORY_SCOPE_AGENT);
      }
      (void)__hip_atomic_load(&FLG[SID*16], __ATOMIC_ACQUIRE,
                              __HIP_MEMORY_SCOPE_AGENT);
    }
    __syncthreads();

    // stage A-matrix into XA (sc1 ring loads: LLC-fresh)
    {
      uint16_t* dst = XA + rowg * RS;
      if constexpr (LAYER == 0){
        const uint16_t* src = R0g + (size_t)((((t+3)&3)*32) + rowg)*240;  // h0(t-1)
        const uint32_t* s32 = (const uint32_t*)src;
        for (int pc = cg; pc < 115; pc += 16){
          uint32_t v = ldg32(s32 + pc);
          dst[1 + 2*pc] = (uint16_t)v;
          dst[2 + 2*pc] = (uint16_t)(v >> 16);
        }
        if (cg == 0){
          dst[231] = ldg16(src + 230);
          dst[0] = bfbits(elapsed[(size_t)(b0 + rowg)*T_ + t]);           // x_t
        }
      } else if constexpr (LAYER == 1){
        const uint16_t* s0 = R0g + (size_t)(((t&3)*32) + rowg)*240;       // n0(t)
        const uint32_t* s032 = (const uint32_t*)s0;
        for (int pc = cg; pc < 115; pc += 16)
          *(uint32_t*)(dst + 2*pc) = ldg32(s032 + pc);
        const uint16_t* s1 = R1g + (size_t)((((t+3)&3)*32) + rowg)*160;   // h1(t-1)
        const uint32_t* s132 = (const uint32_t*)s1;
        for (int jc = cg; jc < 76; jc += 16){
          uint32_t v = ldg32(s132 + jc);
          dst[231 + 2*jc] = (uint16_t)v;
          dst[232 + 2*jc] = (uint16_t)(v >> 16);
        }
        if (cg == 0){
          dst[230] = ldg16(s0 + 230);
          dst[383] = ldg16(s1 + 152);
        }
      } else {
        const uint16_t* s1 = R1g + (size_t)(((t&3)*32) + rowg)*160;       // n1(t)
        const uint32_t* s132 = (const uint32_t*)s1;
        for (int jc = cg; jc < 76; jc += 16)
          *(uint32_t*)(dst + 2*jc) = ldg32(s132 + jc);
        const uint16_t* s2 = R2g + (size_t)((((t+3)&3)*32) + rowg)*128;   // h2(t-1)
        const uint32_t* s232 = (const uint32_t*)s2;
        for (int jc = cg; jc < 64; jc += 16){
          uint32_t v = ldg32(s232 + jc);
          dst[153 + 2*jc] = (uint16_t)v;
          dst[154 + 2*jc] = (uint16_t)(v >> 16);
        }
        if (cg == 0) dst[152] = ldg16(s1 + 152);
      }
    }
    __syncthreads();

    // compute: wave owns tile NT0+wave (weights from LDS)
    float hsave[8];
    if (wave < NT){
      const int nt = NT0 + wave;
      bf16x8 aL[KT], aH[KT];
      const uint16_t* ar = XA + llo*RS + lhi*8;
      #pragma unroll
      for (int kt = 0; kt < KT; ++kt){
        aL[kt] = *(const bf16x8*)(ar + kt*32);
        aH[kt] = *(const bf16x8*)(ar + 16*RS + kt*32);
      }
      f32x4 cL0 = {0.f,0.f,0.f,0.f}, cL1 = cL0, cL2 = cL0;
      f32x4 cH0 = cL0, cH1 = cL0, cH2 = cL0;
      #pragma unroll
      for (int m = 0; m < 3; ++m){
        const uint16_t* wb = Wl + (size_t)((m*NT + wave)*KT)*512 + lane*8;
        #pragma unroll
        for (int kt = 0; kt < KT; ++kt){
          bf16x8 w = *(const bf16x8*)(wb + kt*512);
          if (m == 0){ cL0 = __builtin_amdgcn_mfma_f32_16x16x32_bf16(aL[kt], w, cL0,0,0,0);
                       cH0 = __builtin_amdgcn_mfma_f32_16x16x32_bf16(aH[kt], w, cH0,0,0,0); }
          else if (m == 1){ cL1 = __builtin_amdgcn_mfma_f32_16x16x32_bf16(aL[kt], w, cL1,0,0,0);
                            cH1 = __builtin_amdgcn_mfma_f32_16x16x32_bf16(aH[kt], w, cH1,0,0,0); }
          else { cL2 = __builtin_amdgcn_mfma_f32_16x16x32_bf16(aL[kt], w, cL2,0,0,0);
                 cH2 = __builtin_amdgcn_mfma_f32_16x16x32_bf16(aH[kt], w, cH2,0,0,0); }
        }
      }
      // epilogue: gates; sc1 ring writes; out values buffered to hsave
      const int j = nt*16 + llo;
      uint16_t* rs = RNGg + (size_t)((t&3)*32)*RC;
      #pragma unroll
      for (int half = 0; half < 2; ++half){
        const f32x4& c0 = half ? cH0 : cL0;
        const f32x4& c1 = half ? cH1 : cL1;
        const f32x4& c2 = half ? cH2 : cL2;
        #pragma unroll
        for (int r = 0; r < 4; ++r){
          const int row = half*16 + lhi*4 + r;
          float ff1 = tanh_f(c0[r] + bs0);
          float ff2 = tanh_f(c1[r] + bs1);
          float tt  = sigm_f(c2[r] + bs2);
          float h = ff1 + tt*(ff2 - ff1);
          stg16(&rs[(size_t)row*RC + j], bfbits(h));
          hsave[half*4 + r] = h;
        }
      }
    }

    DRAIN();                       // ring stores at LLC
    __syncthreads();
    if (tid == 0)                  // relaxed flag: ordering via the drain
      __hip_atomic_store(&FLG[SID*16], t+2, __ATOMIC_RELAXED, __HIP_MEMORY_SCOPE_AGENT);

    // post-flag global stores (off the critical path)
    if (wave < NT){
      const int j = (NT0 + wave)*16 + llo;
      if constexpr (LAYER == 2){
        #pragma unroll
        for (int half = 0; half < 2; ++half)
          #pragma unroll
          for (int r = 0; r < 4; ++r){
            const int row = half*16 + lhi*4 + r;
            out[((size_t)(b0+row)*T_ + t)*128 + j] = hsave[half*4 + r];
          }
      }
      if (t == T_-1 && j < SCOL){
        #pragma unroll
        for (int half = 0; half < 2; ++half)
          #pragma unroll
          for (int r = 0; r < 4; ++r){
            const int row = half*16 + lhi*4 + r;
            out[OH + (size_t)(b0+row)*512 + CBASE + j] = hsave[half*4 + r];
          }
      }
    }
  };

  #pragma unroll 1
  for (int t = 0; t < T_; ++t){
    phase(FLGA, R0A, R1A, R2A, RNGA, gA*32, t);
    phase(FLGB, R0B, R1B, R2B, RNGB, gB*32, t);
  }
}

__global__ __launch_bounds__(512) void cfc_pipe(
    const float* __restrict__ elapsed, const float* __restrict__ enc,
    const float* __restrict__ b1_0, const float* __restrict__ b2_0,
    const float* __restrict__ ba0,  const float* __restrict__ bb0,
    const float* __restrict__ b1_1, const float* __restrict__ b2_1,
    const float* __restrict__ ba1,  const float* __restrict__ bb1,
    const float* __restrict__ b1_2, const float* __restrict__ b2_2,
    const float* __restrict__ ba2,  const float* __restrict__ bb2,
    const uint16_t* __restrict__ Wp, uint8_t* __restrict__ wsb,
    float* __restrict__ out)
{
  __shared__ uint16_t Wl[61440];       // 122880 B (max stage weight shard)
  __shared__ uint16_t XA[32*392];      // 25088 B  -> 147968 B total, 1 block/CU

  const int bid = blockIdx.x;
  const int p = bid & 7, s = bid >> 3;    // pair p on XCD p; stages s=0..8
  const int gA = p, gB = p + 8;
  const int tid = threadIdx.x;

  switch (s){
    case 0: stage_run<0>(gA, gB, tid, elapsed, enc, b1_0, b2_0, ba0, bb0, Wp, wsb, out, Wl, XA); break;
    case 1: stage_run<1>(gA, gB, tid, elapsed, enc, b1_0, b2_0, ba0, bb0, Wp, wsb, out, Wl, XA); break;
    case 2: stage_run<2>(gA, gB, tid, elapsed, enc, b1_0, b2_0, ba0, bb0, Wp, wsb, out, Wl, XA); break;
    case 3: stage_run<3>(gA, gB, tid, elapsed, enc, b1_1, b2_1, ba1, bb1, Wp, wsb, out, Wl, XA); break;
    case 4: stage_run<4>(gA, gB, tid, elapsed, enc, b1_1, b2_1, ba1, bb1, Wp, wsb, out, Wl, XA); break;
    case 5: stage_run<5>(gA, gB, tid, elapsed, enc, b1_1, b2_1, ba1, bb1, Wp, wsb, out, Wl, XA); break;
    case 6: stage_run<6>(gA, gB, tid, elapsed, enc, b1_1, b2_1, ba1, bb1, Wp, wsb, out, Wl, XA); break;
    case 7: stage_run<7>(gA, gB, tid, elapsed, enc, b1_2, b2_2, ba2, bb2, Wp, wsb, out, Wl, XA); break;
    default: stage_run<8>(gA, gB, tid, elapsed, enc, b1_2, b2_2, ba2, bb2, Wp, wsb, out, Wl, XA); break;
  }
}

extern "C" void kernel_launch(void* const* d_in, const int* in_sizes, int n_in,
                              void* d_out, int out_size, void* d_ws, size_t ws_size,
                              hipStream_t stream)
{
  const float* elapsed = (const float*)d_in[0];
  const float* enc     = (const float*)d_in[1];
  const float* W1_0 = (const float*)d_in[2];  const float* b1_0 = (const float*)d_in[3];
  const float* W2_0 = (const float*)d_in[4];  const float* b2_0 = (const float*)d_in[5];
  const float* Wa0  = (const float*)d_in[6];  const float* ba0  = (const float*)d_in[7];
  const float* Wb0  = (const float*)d_in[8];  const float* bb0  = (const float*)d_in[9];
  const float* M0   = (const float*)d_in[10];
  const float* W1_1 = (const float*)d_in[11]; const float* b1_1 = (const float*)d_in[12];
  const float* W2_1 = (const float*)d_in[13]; const float* b2_1 = (const float*)d_in[14];
  const float* Wa1  = (const float*)d_in[15]; const float* ba1  = (const float*)d_in[16];
  const float* Wb1  = (const float*)d_in[17]; const float* bb1  = (const float*)d_in[18];
  const float* M1   = (const float*)d_in[19];
  const float* W1_2 = (const float*)d_in[20]; const float* b1_2 = (const float*)d_in[21];
  const float* W2_2 = (const float*)d_in[22]; const float* b2_2 = (const float*)d_in[23];
  const float* Wa2  = (const float*)d_in[24]; const float* ba2  = (const float*)d_in[25];
  const float* Wb2  = (const float*)d_in[26]; const float* bb2  = (const float*)d_in[27];
  const float* M2   = (const float*)d_in[28];

  uint8_t*  wsb = (uint8_t*)d_ws;
  uint16_t* wp  = (uint16_t*)d_ws;

  zero_flags<<<5, 512, 0, stream>>>(wsb);
  pack_w<<<90, 256, 0, stream>>>(W1_0, W2_0, Wa0, Wb0, M0, wp,          15,  8, 231, 232);
  pack_w<<<90, 256, 0, stream>>>(W1_1, W2_1, Wa1, Wb1, M1, wp + 184320, 10, 12, 153, 384);
  pack_w<<<54, 256, 0, stream>>>(W1_2, W2_2, Wa2, Wb2, M2, wp + 368640,  8,  9, 128, 281);

  cfc_pipe<<<72, 512, 0, stream>>>(elapsed, enc,
                                   b1_0, b2_0, ba0, bb0,
                                   b1_1, b2_1, ba1, bb1,
                                   b1_2, b2_2, ba2, bb2,
                                   wp, wsb, (float*)d_out);
}

// Round 12
// 3091.327 us; speedup vs baseline: 1.8797x; 1.8797x over previous
//
#include <hip/hip_runtime.h>
#include <stdint.h>

#define B_ 512
#define T_ 512

typedef __attribute__((ext_vector_type(8))) __bf16 bf16x8;
typedef __attribute__((ext_vector_type(4))) float f32x4;
typedef __attribute__((ext_vector_type(8))) unsigned short u16x8;

// d_ws layout (bytes):
//   [0)        packed bf16 weights (pack_w), 958464 u16 = 1916928 B
//   [N0OFF)    R0 ring: 16 groups x 4 slots x 32 rows x 240 cols u16 = 983040 B
//   [N1OFF)    R1 ring: 16 x 4 x 32 x 160 u16 = 655360 B
//   [N2OFF)    R2 ring: 16 x 4 x 32 x 128 u16 = 524288 B
//   [FLOFF)    flags: 16 groups x 9 stages x 16 ints (64B spaced) = 9216 B
#define N0OFF 1916928u
#define N1OFF 2899968u
#define N2OFF 3555328u
#define FLOFF 4079616u

// 9 stages per 32-row group (144 blocks). Weights in LDS (loaded once).
// Rings depth-4; data stores sc1-atomic (LLC write-through); producer: vmcnt
// drain + relaxed flag. Consumer: cached-flag skip, relaxed polls + one
// ACQUIRE per step, staging via relaxed agent atomic loads (R9-proven).
constexpr int L_[9]   = {0,0,0, 1,1,1,1, 2,2};
constexpr int NT0_[9] = {0,5,10, 0,3,6,8, 0,4};
constexpr int NT_[9]  = {5,5,5, 3,3,2,2, 4,4};
constexpr int KT_[3]  = {8,12,9};
constexpr int NPT_[3] = {15,10,8};
constexpr int SC_[3]  = {231,153,128};
constexpr int RS_[3]  = {264,392,296};
constexpr int CB_[3]  = {0,231,384};
constexpr int RC_[3]  = {240,160,128};
constexpr unsigned WOFF_[3] = {0u,184320u,368640u};
// wait lists: flag index (stage within group) + lag (need flag >= t+lag)
constexpr int WN_[9] = {6,6,6, 8,8,8,8, 5,5};
constexpr int WF_[9][8] = {
  {1,2,3,4,5,6,0,0},{0,2,3,4,5,6,0,0},{0,1,3,4,5,6,0,0},
  {0,1,2,4,5,6,7,8},{0,1,2,3,5,6,7,8},{0,1,2,3,4,6,7,8},{0,1,2,3,4,5,7,8},
  {3,4,5,6,8,0,0,0},{3,4,5,6,7,0,0,0}};
constexpr int WL_[9][8] = {
  {1,1,-2,-2,-2,-2,0,0},{1,1,-2,-2,-2,-2,0,0},{1,1,-2,-2,-2,-2,0,0},
  {2,2,2,1,1,1,-2,-2},{2,2,2,1,1,1,-2,-2},{2,2,2,1,1,1,-2,-2},{2,2,2,1,1,1,-2,-2},
  {2,2,2,2,1,0,0,0},{2,2,2,2,1,0,0,0}};

static __device__ __forceinline__ uint16_t bfbits(float f){
  __bf16 h = (__bf16)f; return __builtin_bit_cast(uint16_t, h);
}
static __device__ __forceinline__ float sigm_f(float x){
  return __builtin_amdgcn_rcpf(1.0f + __builtin_amdgcn_exp2f(-1.4426950408889634f*x));
}
static __device__ __forceinline__ float tanh_f(float x){
  return 2.0f*__builtin_amdgcn_rcpf(1.0f + __builtin_amdgcn_exp2f(-2.8853900817779268f*x)) - 1.0f;
}
static __device__ __forceinline__ uint32_t ldg32(const uint32_t* p){
  return __hip_atomic_load(p, __ATOMIC_RELAXED, __HIP_MEMORY_SCOPE_AGENT);
}
static __device__ __forceinline__ uint16_t ldg16(const uint16_t* p){
  return __hip_atomic_load(p, __ATOMIC_RELAXED, __HIP_MEMORY_SCOPE_AGENT);
}
static __device__ __forceinline__ void stg16(uint16_t* p, uint16_t v){
  __hip_atomic_store(p, v, __ATOMIC_RELAXED, __HIP_MEMORY_SCOPE_AGENT);  // sc1
}
#define DRAIN() asm volatile("s_waitcnt vmcnt(0)" ::: "memory")

__global__ void zero_flags(uint8_t* wsb){
  int i = blockIdx.x*512 + threadIdx.x;
  if (i < 2304) ((int*)(wsb + FLOFF))[i] = 0;
}

__global__ void pack_w(const float* __restrict__ W1, const float* __restrict__ W2,
                       const float* __restrict__ Wa, const float* __restrict__ Wb,
                       const float* __restrict__ Msk, uint16_t* __restrict__ dst,
                       int NPT, int KT, int S, int C)
{
  int c = blockIdx.x * 256 + threadIdx.x;
  int chunks = 3 * NPT * KT * 64;
  if (c >= chunks) return;
  int perN = KT * 64;
  int n3 = c / perN, r = c % perN;
  int kt = r >> 6, lane = r & 63;
  int m = n3 / NPT, nt = n3 % NPT;
  int j = nt * 16 + (lane & 15);
  int kb = kt * 32 + (lane >> 4) * 8;
  u16x8 o;
  #pragma unroll
  for (int i = 0; i < 8; ++i){
    int k = kb + i;
    float v = 0.f;
    if (j < S && k < C){
      size_t idx = (size_t)j * C + k;
      if (m == 0)      v = W1[idx] * Msk[idx];
      else if (m == 1) v = W2[idx] * Msk[idx];
      else             v = Wa[idx] + Wb[idx];
    }
    o[i] = bfbits(v);
  }
  *(u16x8*)(dst + (size_t)c * 8) = o;
}

template<int SID>
__device__ __forceinline__ void stage_run(
    int g, int tid,
    const float* __restrict__ elapsed, const float* __restrict__ enc,
    const float* __restrict__ bp1, const float* __restrict__ bp2,
    const float* __restrict__ bpa, const float* __restrict__ bpb,
    const uint16_t* __restrict__ Wp, uint8_t* __restrict__ wsb,
    float* __restrict__ out, uint16_t* Wl, uint16_t* XA)
{
  constexpr int LAYER = L_[SID];
  constexpr int NT0 = NT0_[SID], NT = NT_[SID];
  constexpr int KT = KT_[LAYER], NPT = NPT_[LAYER];
  constexpr int SCOL = SC_[LAYER], RS = RS_[LAYER];
  constexpr int CBASE = CB_[LAYER], RC = RC_[LAYER];

  const int wave = tid >> 6, lane = tid & 63, llo = lane & 15, lhi = lane >> 4;
  const int rowg = tid >> 4, cg = tid & 15;       // 32 rows x 16 threads
  const int b0 = g * 32;

  uint16_t* R0 = (uint16_t*)(wsb + N0OFF) + (size_t)g * (4*32*240);
  uint16_t* R1 = (uint16_t*)(wsb + N1OFF) + (size_t)g * (4*32*160);
  uint16_t* R2 = (uint16_t*)(wsb + N2OFF) + (size_t)g * (4*32*128);
  int* FLG = (int*)(wsb + FLOFF) + g * (9*16);
  uint16_t* RNG = (LAYER==0) ? R0 : (LAYER==1) ? R1 : R2;

  // ---- weights: global (packed) -> LDS, once ----
  {
    const u16x8* Wp8 = (const u16x8*)(Wp + WOFF_[LAYER]);
    u16x8* Wl8 = (u16x8*)Wl;
    constexpr int CHUNKS = 3 * NT * KT * 64;
    for (int c = tid; c < CHUNKS; c += 512){
      int m = c / (NT*KT*64), r = c - m*(NT*KT*64);
      int tl = r / (KT*64),  r2 = r - tl*(KT*64);
      Wl8[c] = Wp8[(size_t)((m*NPT + NT0 + tl)*KT*64) + r2];
    }
  }
  // ---- XA zero (K-pad columns must stay 0) ----
  for (int i = tid; i < 32*RS; i += 512) XA[i] = 0;

  // ---- biases -> registers (wave owns tile NT0+wave) ----
  float bs0 = 0.f, bs1 = 0.f, bs2 = 0.f;
  if (wave < NT){
    const int j = (NT0 + wave)*16 + llo;
    if (j < SCOL){ bs0 = bp1[j]; bs1 = bp2[j]; bs2 = bpa[j] + bpb[j]; }
  }

  // ---- init own h-slice (state -1) into ring slot 3 (sc1 stores) ----
  for (int idx = tid; idx < 32*NT*16; idx += 512){
    int row = idx / (NT*16), jl = idx % (NT*16);
    int j = NT0*16 + jl;
    float v = 0.f;
    if (j < SCOL){
      if constexpr (LAYER == 0) v = enc[(size_t)(b0+row)*512 + j];
      else if constexpr (LAYER == 1) v = enc[(size_t)(b0+row)*512 + 231 + j];
      else v = enc[(size_t)(b0+row)*512 + 384 + j];
    }
    stg16(&RNG[(size_t)(3*32 + row)*RC + j], bfbits(v));
  }
  DRAIN();
  __syncthreads();
  if (tid == 0){
    __threadfence();   // once: publish init
    __hip_atomic_store(&FLG[SID*16], 1, __ATOMIC_RELEASE, __HIP_MEMORY_SCOPE_AGENT);
  }

  const size_t OH = (size_t)B_ * T_ * 128;

  int fc[8];             // cached flag values (tid 0 only; flags are monotone)
  #pragma unroll
  for (int i = 0; i < 8; ++i) fc[i] = 1;

  #pragma unroll 1
  for (int t = 0; t < T_; ++t){
    // ---- wait: cached-flag skip; relaxed polls only when needed; acquire ----
    if (tid == 0){
      bool need = false;
      #pragma unroll
      for (int i = 0; i < WN_[SID]; ++i) need |= (fc[i] < t + WL_[SID][i]);
      if (need){
        int spin = 0;
        for (;;){
          bool ok = true;
          #pragma unroll
          for (int i = 0; i < WN_[SID]; ++i){
            if (fc[i] < t + WL_[SID][i])
              fc[i] = __hip_atomic_load(&FLG[WF_[SID][i]*16], __ATOMIC_RELAXED,
                                        __HIP_MEMORY_SCOPE_AGENT);
            ok &= (fc[i] >= t + WL_[SID][i]);
          }
          if (ok) break;
          __builtin_amdgcn_s_sleep(1);
          if ((++spin & 31) == 0)   // liveness guard
            (void)__hip_atomic_load(&FLG[WF_[SID][0]*16], __ATOMIC_ACQUIRE,
                                    __HIP_MEMORY_SCOPE_AGENT);
        }
      }
      (void)__hip_atomic_load(&FLG[SID*16], __ATOMIC_ACQUIRE,
                              __HIP_MEMORY_SCOPE_AGENT);
    }
    __syncthreads();

    // ---- stage A-matrix into XA (relaxed agent loads: LLC-fresh) ----
    {
      uint16_t* dst = XA + rowg * RS;
      if constexpr (LAYER == 0){
        const uint16_t* src = R0 + (size_t)((((t+3)&3)*32) + rowg)*240;  // h0(t-1)
        const uint32_t* s32 = (const uint32_t*)src;
        for (int pc = cg; pc < 115; pc += 16){
          uint32_t v = ldg32(s32 + pc);
          dst[1 + 2*pc] = (uint16_t)v;
          dst[2 + 2*pc] = (uint16_t)(v >> 16);
        }
        if (cg == 0){
          dst[231] = ldg16(src + 230);
          dst[0] = bfbits(elapsed[(size_t)(b0 + rowg)*T_ + t]);          // x_t
        }
      } else if constexpr (LAYER == 1){
        const uint16_t* s0 = R0 + (size_t)(((t&3)*32) + rowg)*240;       // n0(t)
        const uint32_t* s032 = (const uint32_t*)s0;
        for (int pc = cg; pc < 115; pc += 16)
          *(uint32_t*)(dst + 2*pc) = ldg32(s032 + pc);
        const uint16_t* s1 = R1 + (size_t)((((t+3)&3)*32) + rowg)*160;   // h1(t-1)
        const uint32_t* s132 = (const uint32_t*)s1;
        for (int jc = cg; jc < 76; jc += 16){
          uint32_t v = ldg32(s132 + jc);
          dst[231 + 2*jc] = (uint16_t)v;
          dst[232 + 2*jc] = (uint16_t)(v >> 16);
        }
        if (cg == 0){
          dst[230] = ldg16(s0 + 230);
          dst[383] = ldg16(s1 + 152);
        }
      } else {
        const uint16_t* s1 = R1 + (size_t)(((t&3)*32) + rowg)*160;       // n1(t)
        const uint32_t* s132 = (const uint32_t*)s1;
        for (int jc = cg; jc < 76; jc += 16)
          *(uint32_t*)(dst + 2*jc) = ldg32(s132 + jc);
        const uint16_t* s2 = R2 + (size_t)((((t+3)&3)*32) + rowg)*128;   // h2(t-1)
        const uint32_t* s232 = (const uint32_t*)s2;
        for (int jc = cg; jc < 64; jc += 16){
          uint32_t v = ldg32(s232 + jc);
          dst[153 + 2*jc] = (uint16_t)v;
          dst[154 + 2*jc] = (uint16_t)(v >> 16);
        }
        if (cg == 0) dst[152] = ldg16(s1 + 152);
      }
    }
    __syncthreads();

    // ---- compute: wave owns tile NT0+wave (weights from LDS) ----
    float hsave[8];
    if (wave < NT){
      const int nt = NT0 + wave;
      bf16x8 aL[KT], aH[KT];
      const uint16_t* ar = XA + llo*RS + lhi*8;
      #pragma unroll
      for (int kt = 0; kt < KT; ++kt){
        aL[kt] = *(const bf16x8*)(ar + kt*32);
        aH[kt] = *(const bf16x8*)(ar + 16*RS + kt*32);
      }
      f32x4 cL0 = {0.f,0.f,0.f,0.f}, cL1 = cL0, cL2 = cL0;
      f32x4 cH0 = cL0, cH1 = cL0, cH2 = cL0;
      #pragma unroll
      for (int m = 0; m < 3; ++m){
        const uint16_t* wb = Wl + (size_t)((m*NT + wave)*KT)*512 + lane*8;
        #pragma unroll
        for (int kt = 0; kt < KT; ++kt){
          bf16x8 w = *(const bf16x8*)(wb + kt*512);
          if (m == 0){ cL0 = __builtin_amdgcn_mfma_f32_16x16x32_bf16(aL[kt], w, cL0,0,0,0);
                       cH0 = __builtin_amdgcn_mfma_f32_16x16x32_bf16(aH[kt], w, cH0,0,0,0); }
          else if (m == 1){ cL1 = __builtin_amdgcn_mfma_f32_16x16x32_bf16(aL[kt], w, cL1,0,0,0);
                            cH1 = __builtin_amdgcn_mfma_f32_16x16x32_bf16(aH[kt], w, cH1,0,0,0); }
          else { cL2 = __builtin_amdgcn_mfma_f32_16x16x32_bf16(aL[kt], w, cL2,0,0,0);
                 cH2 = __builtin_amdgcn_mfma_f32_16x16x32_bf16(aH[kt], w, cH2,0,0,0); }
        }
      }
      // epilogue: gates; sc1 ring writes on drain path; out deferred to hsave
      const int j = nt*16 + llo;
      uint16_t* rs = RNG + (size_t)((t&3)*32)*RC;
      #pragma unroll
      for (int half = 0; half < 2; ++half){
        const f32x4& c0 = half ? cH0 : cL0;
        const f32x4& c1 = half ? cH1 : cL1;
        const f32x4& c2 = half ? cH2 : cL2;
        #pragma unroll
        for (int r = 0; r < 4; ++r){
          const int row = half*16 + lhi*4 + r;
          float ff1 = tanh_f(c0[r] + bs0);
          float ff2 = tanh_f(c1[r] + bs1);
          float tt  = sigm_f(c2[r] + bs2);
          float h = ff1 + tt*(ff2 - ff1);
          stg16(&rs[(size_t)row*RC + j], bfbits(h));
          hsave[half*4 + r] = h;
        }
      }
    }

    DRAIN();                       // ring stores at LLC
    __syncthreads();
    if (tid == 0)                  // relaxed flag: ordering via the drain
      __hip_atomic_store(&FLG[SID*16], t+2, __ATOMIC_RELAXED, __HIP_MEMORY_SCOPE_AGENT);

    // ---- post-publish global stores (off the critical path; R10-proven) ----
    if (wave < NT){
      const int j = (NT0 + wave)*16 + llo;
      if constexpr (LAYER == 2){
        #pragma unroll
        for (int half = 0; half < 2; ++half)
          #pragma unroll
          for (int r = 0; r < 4; ++r){
            const int row = half*16 + lhi*4 + r;
            out[((size_t)(b0+row)*T_ + t)*128 + j] = hsave[half*4 + r];
          }
      }
      if (t == T_-1 && j < SCOL){
        #pragma unroll
        for (int half = 0; half < 2; ++half)
          #pragma unroll
          for (int r = 0; r < 4; ++r){
            const int row = half*16 + lhi*4 + r;
            out[OH + (size_t)(b0+row)*512 + CBASE + j] = hsave[half*4 + r];
          }
      }
    }
  }
}

__global__ __launch_bounds__(512) void cfc_pipe(
    const float* __restrict__ elapsed, const float* __restrict__ enc,
    const float* __restrict__ b1_0, const float* __restrict__ b2_0,
    const float* __restrict__ ba0,  const float* __restrict__ bb0,
    const float* __restrict__ b1_1, const float* __restrict__ b2_1,
    const float* __restrict__ ba1,  const float* __restrict__ bb1,
    const float* __restrict__ b1_2, const float* __restrict__ b2_2,
    const float* __restrict__ ba2,  const float* __restrict__ bb2,
    const uint16_t* __restrict__ Wp, uint8_t* __restrict__ wsb,
    float* __restrict__ out)
{
  __shared__ uint16_t Wl[61440];       // 122880 B (max stage weight shard)
  __shared__ uint16_t XA[32*392];      // 25088 B  -> 147968 B total, 1 block/CU

  const int bid = blockIdx.x;
  const int g = bid & 15, s = bid >> 4;     // group's 9 stages share XCD g%8
  const int tid = threadIdx.x;

  switch (s){
    case 0: stage_run<0>(g, tid, elapsed, enc, b1_0, b2_0, ba0, bb0, Wp, wsb, out, Wl, XA); break;
    case 1: stage_run<1>(g, tid, elapsed, enc, b1_0, b2_0, ba0, bb0, Wp, wsb, out, Wl, XA); break;
    case 2: stage_run<2>(g, tid, elapsed, enc, b1_0, b2_0, ba0, bb0, Wp, wsb, out, Wl, XA); break;
    case 3: stage_run<3>(g, tid, elapsed, enc, b1_1, b2_1, ba1, bb1, Wp, wsb, out, Wl, XA); break;
    case 4: stage_run<4>(g, tid, elapsed, enc, b1_1, b2_1, ba1, bb1, Wp, wsb, out, Wl, XA); break;
    case 5: stage_run<5>(g, tid, elapsed, enc, b1_1, b2_1, ba1, bb1, Wp, wsb, out, Wl, XA); break;
    case 6: stage_run<6>(g, tid, elapsed, enc, b1_1, b2_1, ba1, bb1, Wp, wsb, out, Wl, XA); break;
    case 7: stage_run<7>(g, tid, elapsed, enc, b1_2, b2_2, ba2, bb2, Wp, wsb, out, Wl, XA); break;
    default: stage_run<8>(g, tid, elapsed, enc, b1_2, b2_2, ba2, bb2, Wp, wsb, out, Wl, XA); break;
  }
}

extern "C" void kernel_launch(void* const* d_in, const int* in_sizes, int n_in,
                              void* d_out, int out_size, void* d_ws, size_t ws_size,
                              hipStream_t stream)
{
  const float* elapsed = (const float*)d_in[0];
  const float* enc     = (const float*)d_in[1];
  const float* W1_0 = (const float*)d_in[2];  const float* b1_0 = (const float*)d_in[3];
  const float* W2_0 = (const float*)d_in[4];  const float* b2_0 = (const float*)d_in[5];
  const float* Wa0  = (const float*)d_in[6];  const float* ba0  = (const float*)d_in[7];
  const float* Wb0  = (const float*)d_in[8];  const float* bb0  = (const float*)d_in[9];
  const float* M0   = (const float*)d_in[10];
  const float* W1_1 = (const float*)d_in[11]; const float* b1_1 = (const float*)d_in[12];
  const float* W2_1 = (const float*)d_in[13]; const float* b2_1 = (const float*)d_in[14];
  const float* Wa1  = (const float*)d_in[15]; const float* ba1  = (const float*)d_in[16];
  const float* Wb1  = (const float*)d_in[17]; const float* bb1  = (const float*)d_in[18];
  const float* M1   = (const float*)d_in[19];
  const float* W1_2 = (const float*)d_in[20]; const float* b1_2 = (const float*)d_in[21];
  const float* W2_2 = (const float*)d_in[22]; const float* b2_2 = (const float*)d_in[23];
  const float* Wa2  = (const float*)d_in[24]; const float* ba2  = (const float*)d_in[25];
  const float* Wb2  = (const float*)d_in[26]; const float* bb2  = (const float*)d_in[27];
  const float* M2   = (const float*)d_in[28];

  uint8_t*  wsb = (uint8_t*)d_ws;
  uint16_t* wp  = (uint16_t*)d_ws;

  zero_flags<<<5, 512, 0, stream>>>(wsb);
  pack_w<<<90, 256, 0, stream>>>(W1_0, W2_0, Wa0, Wb0, M0, wp,          15,  8, 231, 232);
  pack_w<<<90, 256, 0, stream>>>(W1_1, W2_1, Wa1, Wb1, M1, wp + 184320, 10, 12, 153, 384);
  pack_w<<<54, 256, 0, stream>>>(W1_2, W2_2, Wa2, Wb2, M2, wp + 368640,  8,  9, 128, 281);

  cfc_pipe<<<144, 512, 0, stream>>>(elapsed, enc,
                                    b1_0, b2_0, ba0, bb0,
                                    b1_1, b2_1, ba1, bb1,
                                    b1_2, b2_2, ba2, bb2,
                                    wp, wsb, (float*)d_out);
}

// Round 13
// 2434.110 us; speedup vs baseline: 2.3872x; 1.2700x over previous
//
#include <hip/hip_runtime.h>
#include <stdint.h>

#define B_ 512
#define T_ 512

typedef __attribute__((ext_vector_type(8))) __bf16 bf16x8;
typedef __attribute__((ext_vector_type(4))) float f32x4;
typedef __attribute__((ext_vector_type(8))) unsigned short u16x8;

// d_ws layout (bytes):
//   [0)        packed bf16 weights (pack_w), 958464 u16 = 1916928 B
//   [N0OFF)    R0 ring: 16 groups x 4 slots x 32 rows x 312 u16 = 1277952 B
//   [N1OFF)    R1 ring: 16 x 4 x 32 x 208 u16 = 851968 B
//   [N2OFF)    R2 ring: 16 x 4 x 32 x 176 u16 = 720896 B
//   [FLOFF)    flags: 16 groups x 9 stages x 16 ints = 9216 B
#define N0OFF 1916928u
#define N1OFF 3194880u
#define N2OFF 4046848u
#define FLOFF 4767744u

// Tagged-chunk protocol: ring data moves as 8B chunks {p0,p1,p2,tag} written
// and read with single 64-bit agent atomics. tag == producing step (u16;
// init state -1 => 0xFFFF). Tag validity <=> payload validity (single-copy
// atomicity), so NO drain / NO acquire / NO forward flags are needed.
// Flags remain only for backpressure (all lags <= -1, cache-satisfiable).
// Each stage's own h-slice is staged from LDS (HST), not from the ring.
constexpr int L_[9]   = {0,0,0, 1,1,1,1, 2,2};
constexpr int NT0_[9] = {0,5,10, 0,3,6,8, 0,4};
constexpr int NT_[9]  = {5,5,5, 3,3,2,2, 4,4};
constexpr int KT_[3]  = {8,12,9};
constexpr int NPT_[3] = {15,10,8};
constexpr int SC_[3]  = {231,153,128};
constexpr int RS_[3]  = {264,392,296};
constexpr int CB_[3]  = {0,231,384};
constexpr unsigned WOFF_[3] = {0u,184320u,368640u};
// chunk-region tables (per SID): offset/count/valid within the layer row
constexpr int RGO_[9] = {0,27,54, 0,16,32,43, 0,22};
constexpr int RGC_[9] = {27,27,24, 16,16,11,9, 22,22};
constexpr int RGV_[9] = {80,80,71, 48,48,32,25, 64,64};
constexpr int RGB_[9] = {0,80,160, 0,48,96,128, 0,64};
constexpr int RCH4_[3] = {312,208,176};      // ring row stride (u16) = chunks*4
// backpressure wait lists: need FLG[WF] >= t + WL (WL <= -1 always)
constexpr int WN_[9] = {6,6,6, 5,5,5,5, 1,1};
constexpr int WF_[9][6] = {
  {1,2,3,4,5,6},{0,2,3,4,5,6},{0,1,3,4,5,6},
  {4,5,6,7,8,0},{3,5,6,7,8,0},{3,4,6,7,8,0},{3,4,5,7,8,0},
  {8,0,0,0,0,0},{7,0,0,0,0,0}};
constexpr int WL_[9][6] = {
  {-1,-1,-2,-2,-2,-2},{-1,-1,-2,-2,-2,-2},{-1,-1,-2,-2,-2,-2},
  {-1,-1,-1,-2,-2,0},{-1,-1,-1,-2,-2,0},{-1,-1,-1,-2,-2,0},{-1,-1,-1,-2,-2,0},
  {-1,0,0,0,0,0},{-1,0,0,0,0,0}};

static __device__ __forceinline__ uint16_t bfbits(float f){
  __bf16 h = (__bf16)f; return __builtin_bit_cast(uint16_t, h);
}
static __device__ __forceinline__ float sigm_f(float x){
  return __builtin_amdgcn_rcpf(1.0f + __builtin_amdgcn_exp2f(-1.4426950408889634f*x));
}
static __device__ __forceinline__ float tanh_f(float x){
  return 2.0f*__builtin_amdgcn_rcpf(1.0f + __builtin_amdgcn_exp2f(-2.8853900817779268f*x)) - 1.0f;
}
static __device__ __forceinline__ uint64_t ldg64(const uint16_t* p){
  return __hip_atomic_load((const unsigned long long*)p, __ATOMIC_RELAXED,
                           __HIP_MEMORY_SCOPE_AGENT);
}
static __device__ __forceinline__ void stg64(uint16_t* p, uint64_t v){
  __hip_atomic_store((unsigned long long*)p, v, __ATOMIC_RELAXED,
                     __HIP_MEMORY_SCOPE_AGENT);
}
// lgkm-only barrier: LDS ordered; global ops stay in flight.
#define BAR() do { asm volatile("s_waitcnt lgkmcnt(0)" ::: "memory"); \
                   __builtin_amdgcn_s_barrier(); } while(0)
#define DRAIN() asm volatile("s_waitcnt vmcnt(0)" ::: "memory")

__global__ void zero_flags(uint8_t* wsb){
  int i = blockIdx.x*512 + threadIdx.x;
  if (i < 2304) ((int*)(wsb + FLOFF))[i] = 0;
}

__global__ void pack_w(const float* __restrict__ W1, const float* __restrict__ W2,
                       const float* __restrict__ Wa, const float* __restrict__ Wb,
                       const float* __restrict__ Msk, uint16_t* __restrict__ dst,
                       int NPT, int KT, int S, int C)
{
  int c = blockIdx.x * 256 + threadIdx.x;
  int chunks = 3 * NPT * KT * 64;
  if (c >= chunks) return;
  int perN = KT * 64;
  int n3 = c / perN, r = c % perN;
  int kt = r >> 6, lane = r & 63;
  int m = n3 / NPT, nt = n3 % NPT;
  int j = nt * 16 + (lane & 15);
  int kb = kt * 32 + (lane >> 4) * 8;
  u16x8 o;
  #pragma unroll
  for (int i = 0; i < 8; ++i){
    int k = kb + i;
    float v = 0.f;
    if (j < S && k < C){
      size_t idx = (size_t)j * C + k;
      if (m == 0)      v = W1[idx] * Msk[idx];
      else if (m == 1) v = W2[idx] * Msk[idx];
      else             v = Wa[idx] + Wb[idx];
    }
    o[i] = bfbits(v);
  }
  *(u16x8*)(dst + (size_t)c * 8) = o;
}

template<int SID>
__device__ __forceinline__ void stage_run(
    int g, int tid,
    const float* __restrict__ elapsed, const float* __restrict__ enc,
    const float* __restrict__ bp1, const float* __restrict__ bp2,
    const float* __restrict__ bpa, const float* __restrict__ bpb,
    const uint16_t* __restrict__ Wp, uint8_t* __restrict__ wsb,
    float* __restrict__ out, uint16_t* Wl, uint16_t* XA, uint16_t* HST)
{
  constexpr int LAYER = L_[SID];
  constexpr int NT0 = NT0_[SID], NT = NT_[SID];
  constexpr int KT = KT_[LAYER], NPT = NPT_[LAYER];
  constexpr int SCOL = SC_[LAYER], RS = RS_[LAYER];
  constexpr int CBASE = CB_[LAYER];
  constexpr int NCH = RGC_[SID], RGO = RGO_[SID], RGV = RGV_[SID], RGB = RGB_[SID];
  constexpr int RCH4 = RCH4_[LAYER];

  const int wave = tid >> 6, lane = tid & 63, llo = lane & 15, lhi = lane >> 4;
  const int rowg = tid >> 4, cg = tid & 15;       // 32 rows x 16 threads
  const int b0 = g * 32;

  uint16_t* R0 = (uint16_t*)(wsb + N0OFF) + (size_t)g * 39936;
  uint16_t* R1 = (uint16_t*)(wsb + N1OFF) + (size_t)g * 26624;
  uint16_t* R2 = (uint16_t*)(wsb + N2OFF) + (size_t)g * 22528;
  int* FLG = (int*)(wsb + FLOFF) + g * (9*16);
  uint16_t* RNG = (LAYER==0) ? R0 : (LAYER==1) ? R1 : R2;

  // ---- weights: global (packed) -> LDS, once ----
  {
    const u16x8* Wp8 = (const u16x8*)(Wp + WOFF_[LAYER]);
    u16x8* Wl8 = (u16x8*)Wl;
    constexpr int CHUNKS = 3 * NT * KT * 64;
    for (int c = tid; c < CHUNKS; c += 512){
      int m = c / (NT*KT*64), r = c - m*(NT*KT*64);
      int tl = r / (KT*64),  r2 = r - tl*(KT*64);
      Wl8[c] = Wp8[(size_t)((m*NPT + NT0 + tl)*KT*64) + r2];
    }
  }
  for (int i = tid; i < 32*RS; i += 512) XA[i] = 0;   // pads stay 0 forever

  // ---- biases -> registers ----
  float bs0 = 0.f, bs1 = 0.f, bs2 = 0.f;
  if (wave < NT){
    const int j = (NT0 + wave)*16 + llo;
    if (j < SCOL){ bs0 = bp1[j]; bs1 = bp2[j]; bs2 = bpa[j] + bpb[j]; }
  }

  // ---- chunk-store from HST (payload 3 u16 + tag) ----
  auto chunk_store = [&](int slot, uint16_t tag){
    for (int idx = tid; idx < 32*NCH; idx += 512){
      int row = idx / NCH, c = idx - row*NCH;
      int lc = 3*c;
      uint16_t p0 = (lc+0 < RGV) ? HST[row*80 + lc+0] : (uint16_t)0;
      uint16_t p1 = (lc+1 < RGV) ? HST[row*80 + lc+1] : (uint16_t)0;
      uint16_t p2 = (lc+2 < RGV) ? HST[row*80 + lc+2] : (uint16_t)0;
      uint64_t v = (uint64_t)p0 | ((uint64_t)p1<<16) | ((uint64_t)p2<<32)
                 | ((uint64_t)tag<<48);
      stg64(RNG + (size_t)(slot*32 + row)*RCH4 + (size_t)(RGO + c)*4, v);
    }
  };

  // ---- init: state -1 -> HST -> ring slot 3 with tag 0xFFFF ----
  for (int idx = tid; idx < 32*NT*16; idx += 512){
    int row = idx / (NT*16), lc = idx % (NT*16);
    int j = RGB + lc;
    float v = (j < SCOL) ? enc[(size_t)(b0+row)*512 + CBASE + j] : 0.f;
    HST[row*80 + lc] = bfbits(v);
  }
  __syncthreads();
  chunk_store(3, 0xFFFFu);
  DRAIN();
  __syncthreads();
  if (tid == 0)
    __hip_atomic_store(&FLG[SID*16], 1, __ATOMIC_RELAXED, __HIP_MEMORY_SCOPE_AGENT);

  const size_t OH = (size_t)B_ * T_ * 128;

  int fc[6];
  #pragma unroll
  for (int i = 0; i < 6; ++i) fc[i] = 1;

  #pragma unroll 1
  for (int t = 0; t < T_; ++t){
    // ---- backpressure wait (cached, relaxed, no acquire) ----
    if (tid == 0){
      bool need = false;
      #pragma unroll
      for (int i = 0; i < WN_[SID]; ++i) need |= (fc[i] < t + WL_[SID][i]);
      if (need){
        int spin = 0;
        for (;;){
          bool ok = true;
          #pragma unroll
          for (int i = 0; i < WN_[SID]; ++i){
            if (fc[i] < t + WL_[SID][i])
              fc[i] = __hip_atomic_load(&FLG[WF_[SID][i]*16], __ATOMIC_RELAXED,
                                        __HIP_MEMORY_SCOPE_AGENT);
            ok &= (fc[i] >= t + WL_[SID][i]);
          }
          if (ok) break;
          __builtin_amdgcn_s_sleep(1);
          if ((++spin & 63) == 0)   // rare liveness guard
            (void)__hip_atomic_load(&FLG[WF_[SID][0]*16], __ATOMIC_ACQUIRE,
                                    __HIP_MEMORY_SCOPE_AGENT);
        }
      }
    }
    BAR();

    // ---- staging: own slice from HST(LDS); peers via tagged spin-gather ----
    {
      uint16_t* drow = XA + rowg * RS;
      constexpr int DST0 = (LAYER==0) ? 1 : (LAYER==1) ? 231 : 153;
      // own-region copy (h of previous step, still in HST)
      for (int lc = cg; lc < RGV; lc += 16)
        drow[DST0 + RGB + lc] = HST[rowg*80 + lc];

      const uint16_t eN = (uint16_t)t, eH = (uint16_t)(t-1);
      if constexpr (LAYER == 0){
        const uint16_t* rb = R0 + (size_t)((((t+3)&3)*32) + rowg) * 312;
        constexpr int OLO = RGO, OHI = RGO + NCH;
        uint64_t v[5]; uint32_t pend = 0;
        #pragma unroll
        for (int i = 0; i < 5; ++i){
          int c = cg + 16*i;
          if (c < 78 && !(c >= OLO && c < OHI)) pend |= 1u<<i;
        }
        while (pend){
          #pragma unroll
          for (int i = 0; i < 5; ++i)
            if (pend & (1u<<i)) v[i] = ldg64(rb + 4*(cg + 16*i));
          uint32_t np = 0;
          #pragma unroll
          for (int i = 0; i < 5; ++i)
            if ((pend & (1u<<i)) && (uint16_t)(v[i]>>48) != eH) np |= 1u<<i;
          pend = np;
          if (pend) __builtin_amdgcn_s_sleep(1);
        }
        #pragma unroll
        for (int i = 0; i < 5; ++i){
          int c = cg + 16*i;
          if (c >= 78 || (c >= OLO && c < OHI)) continue;
          int rgb, rgv, cr;
          if (c < 27){ rgb=0; rgv=80; cr=c; }
          else if (c < 54){ rgb=80; rgv=80; cr=c-27; }
          else { rgb=160; rgv=71; cr=c-54; }
          int base = 3*cr;
          if (base+0 < rgv) drow[1 + rgb + base+0] = (uint16_t)(v[i]);
          if (base+1 < rgv) drow[1 + rgb + base+1] = (uint16_t)(v[i]>>16);
          if (base+2 < rgv) drow[1 + rgb + base+2] = (uint16_t)(v[i]>>32);
        }
        if (cg == 0) drow[0] = bfbits(elapsed[(size_t)(b0 + rowg)*T_ + t]);
      } else if constexpr (LAYER == 1){
        const uint16_t* rbA = R0 + (size_t)(((t&3)*32) + rowg) * 312;       // n0(t)
        const uint16_t* rbB = R1 + (size_t)((((t+3)&3)*32) + rowg) * 208;   // h1(t-1)
        constexpr int OLO = RGO, OHI = RGO + NCH;
        uint64_t vA[5], vB[4]; uint32_t pend = 0;
        #pragma unroll
        for (int i = 0; i < 5; ++i){ int c = cg + 16*i; if (c < 78) pend |= 1u<<i; }
        #pragma unroll
        for (int i = 0; i < 4; ++i){
          int c = cg + 16*i;
          if (c < 52 && !(c >= OLO && c < OHI)) pend |= 1u<<(8+i);
        }
        while (pend){
          #pragma unroll
          for (int i = 0; i < 5; ++i)
            if (pend & (1u<<i)) vA[i] = ldg64(rbA + 4*(cg + 16*i));
          #pragma unroll
          for (int i = 0; i < 4; ++i)
            if (pend & (1u<<(8+i))) vB[i] = ldg64(rbB + 4*(cg + 16*i));
          uint32_t np = 0;
          #pragma unroll
          for (int i = 0; i < 5; ++i)
            if ((pend & (1u<<i)) && (uint16_t)(vA[i]>>48) != eN) np |= 1u<<i;
          #pragma unroll
          for (int i = 0; i < 4; ++i)
            if ((pend & (1u<<(8+i))) && (uint16_t)(vB[i]>>48) != eH) np |= 1u<<(8+i);
          pend = np;
          if (pend) __builtin_amdgcn_s_sleep(1);
        }
        #pragma unroll
        for (int i = 0; i < 5; ++i){
          int c = cg + 16*i; if (c >= 78) continue;
          int rgb, rgv, cr;
          if (c < 27){ rgb=0; rgv=80; cr=c; }
          else if (c < 54){ rgb=80; rgv=80; cr=c-27; }
          else { rgb=160; rgv=71; cr=c-54; }
          int base = 3*cr;
          if (base+0 < rgv) drow[rgb + base+0] = (uint16_t)(vA[i]);
          if (base+1 < rgv) drow[rgb + base+1] = (uint16_t)(vA[i]>>16);
          if (base+2 < rgv) drow[rgb + base+2] = (uint16_t)(vA[i]>>32);
        }
        #pragma unroll
        for (int i = 0; i < 4; ++i){
          int c = cg + 16*i;
          if (c >= 52 || (c >= OLO && c < OHI)) continue;
          int rgb, rgv, cr;
          if (c < 16){ rgb=0; rgv=48; cr=c; }
          else if (c < 32){ rgb=48; rgv=48; cr=c-16; }
          else if (c < 43){ rgb=96; rgv=32; cr=c-32; }
          else { rgb=128; rgv=25; cr=c-43; }
          int base = 3*cr;
          if (base+0 < rgv) drow[231 + rgb + base+0] = (uint16_t)(vB[i]);
          if (base+1 < rgv) drow[231 + rgb + base+1] = (uint16_t)(vB[i]>>16);
          if (base+2 < rgv) drow[231 + rgb + base+2] = (uint16_t)(vB[i]>>32);
        }
      } else {
        const uint16_t* rbA = R1 + (size_t)(((t&3)*32) + rowg) * 208;       // n1(t)
        const uint16_t* rbB = R2 + (size_t)((((t+3)&3)*32) + rowg) * 176;   // h2(t-1)
        constexpr int OLO = RGO, OHI = RGO + NCH;
        uint64_t vA[4], vB[3]; uint32_t pend = 0;
        #pragma unroll
        for (int i = 0; i < 4; ++i){ int c = cg + 16*i; if (c < 52) pend |= 1u<<i; }
        #pragma unroll
        for (int i = 0; i < 3; ++i){
          int c = cg + 16*i;
          if (c < 44 && !(c >= OLO && c < OHI)) pend |= 1u<<(8+i);
        }
        while (pend){
          #pragma unroll
          for (int i = 0; i < 4; ++i)
            if (pend & (1u<<i)) vA[i] = ldg64(rbA + 4*(cg + 16*i));
          #pragma unroll
          for (int i = 0; i < 3; ++i)
            if (pend & (1u<<(8+i))) vB[i] = ldg64(rbB + 4*(cg + 16*i));
          uint32_t np = 0;
          #pragma unroll
          for (int i = 0; i < 4; ++i)
            if ((pend & (1u<<i)) && (uint16_t)(vA[i]>>48) != eN) np |= 1u<<i;
          #pragma unroll
          for (int i = 0; i < 3; ++i)
            if ((pend & (1u<<(8+i))) && (uint16_t)(vB[i]>>48) != eH) np |= 1u<<(8+i);
          pend = np;
          if (pend) __builtin_amdgcn_s_sleep(1);
        }
        #pragma unroll
        for (int i = 0; i < 4; ++i){
          int c = cg + 16*i; if (c >= 52) continue;
          int rgb, rgv, cr;
          if (c < 16){ rgb=0; rgv=48; cr=c; }
          else if (c < 32){ rgb=48; rgv=48; cr=c-16; }
          else if (c < 43){ rgb=96; rgv=32; cr=c-32; }
          else { rgb=128; rgv=25; cr=c-43; }
          int base = 3*cr;
          if (base+0 < rgv) drow[rgb + base+0] = (uint16_t)(vA[i]);
          if (base+1 < rgv) drow[rgb + base+1] = (uint16_t)(vA[i]>>16);
          if (base+2 < rgv) drow[rgb + base+2] = (uint16_t)(vA[i]>>32);
        }
        #pragma unroll
        for (int i = 0; i < 3; ++i){
          int c = cg + 16*i;
          if (c >= 44 || (c >= OLO && c < OHI)) continue;
          int rgb, cr;
          if (c < 22){ rgb=0; cr=c; } else { rgb=64; cr=c-22; }
          int base = 3*cr;
          if (base+0 < 64) drow[153 + rgb + base+0] = (uint16_t)(vB[i]);
          if (base+1 < 64) drow[153 + rgb + base+1] = (uint16_t)(vB[i]>>16);
          if (base+2 < 64) drow[153 + rgb + base+2] = (uint16_t)(vB[i]>>32);
        }
      }
    }
    BAR();
    if (tid == 0)   // inputs consumed: publish progress (backpressure only)
      __hip_atomic_store(&FLG[SID*16], t+2, __ATOMIC_RELAXED, __HIP_MEMORY_SCOPE_AGENT);

    // ---- compute: wave owns tile NT0+wave (weights from LDS) ----
    float hsave[8];
    if (wave < NT){
      bf16x8 aL[KT], aH[KT];
      const uint16_t* ar = XA + llo*RS + lhi*8;
      #pragma unroll
      for (int kt = 0; kt < KT; ++kt){
        aL[kt] = *(const bf16x8*)(ar + kt*32);
        aH[kt] = *(const bf16x8*)(ar + 16*RS + kt*32);
      }
      f32x4 cL0 = {0.f,0.f,0.f,0.f}, cL1 = cL0, cL2 = cL0;
      f32x4 cH0 = cL0, cH1 = cL0, cH2 = cL0;
      #pragma unroll
      for (int m = 0; m < 3; ++m){
        const uint16_t* wb = Wl + (size_t)((m*NT + wave)*KT)*512 + lane*8;
        #pragma unroll
        for (int kt = 0; kt < KT; ++kt){
          bf16x8 w = *(const bf16x8*)(wb + kt*512);
          if (m == 0){ cL0 = __builtin_amdgcn_mfma_f32_16x16x32_bf16(aL[kt], w, cL0,0,0,0);
                       cH0 = __builtin_amdgcn_mfma_f32_16x16x32_bf16(aH[kt], w, cH0,0,0,0); }
          else if (m == 1){ cL1 = __builtin_amdgcn_mfma_f32_16x16x32_bf16(aL[kt], w, cL1,0,0,0);
                            cH1 = __builtin_amdgcn_mfma_f32_16x16x32_bf16(aH[kt], w, cH1,0,0,0); }
          else { cL2 = __builtin_amdgcn_mfma_f32_16x16x32_bf16(aL[kt], w, cL2,0,0,0);
                 cH2 = __builtin_amdgcn_mfma_f32_16x16x32_bf16(aH[kt], w, cH2,0,0,0); }
        }
      }
      // epilogue: gates -> HST (LDS) + hsave
      #pragma unroll
      for (int half = 0; half < 2; ++half){
        const f32x4& c0 = half ? cH0 : cL0;
        const f32x4& c1 = half ? cH1 : cL1;
        const f32x4& c2 = half ? cH2 : cL2;
        #pragma unroll
        for (int r = 0; r < 4; ++r){
          const int row = half*16 + lhi*4 + r;
          float ff1 = tanh_f(c0[r] + bs0);
          float ff2 = tanh_f(c1[r] + bs1);
          float tt  = sigm_f(c2[r] + bs2);
          float h = ff1 + tt*(ff2 - ff1);
          HST[row*80 + wave*16 + llo] = bfbits(h);
          hsave[half*4 + r] = h;
        }
      }
    }
    BAR();

    // ---- publish: tagged chunk stores (fire-and-forget) ----
    chunk_store(t & 3, (uint16_t)t);

    // ---- global outputs (fire-and-forget) ----
    if (wave < NT){
      const int j = (NT0 + wave)*16 + llo;
      if constexpr (LAYER == 2){
        #pragma unroll
        for (int half = 0; half < 2; ++half)
          #pragma unroll
          for (int r = 0; r < 4; ++r){
            const int row = half*16 + lhi*4 + r;
            out[((size_t)(b0+row)*T_ + t)*128 + j] = hsave[half*4 + r];
          }
      }
      if (t == T_-1 && j < SCOL){
        #pragma unroll
        for (int half = 0; half < 2; ++half)
          #pragma unroll
          for (int r = 0; r < 4; ++r){
            const int row = half*16 + lhi*4 + r;
            out[OH + (size_t)(b0+row)*512 + CBASE + j] = hsave[half*4 + r];
          }
      }
    }
  }
}

__global__ __launch_bounds__(512) void cfc_pipe(
    const float* __restrict__ elapsed, const float* __restrict__ enc,
    const float* __restrict__ b1_0, const float* __restrict__ b2_0,
    const float* __restrict__ ba0,  const float* __restrict__ bb0,
    const float* __restrict__ b1_1, const float* __restrict__ b2_1,
    const float* __restrict__ ba1,  const float* __restrict__ bb1,
    const float* __restrict__ b1_2, const float* __restrict__ b2_2,
    const float* __restrict__ ba2,  const float* __restrict__ bb2,
    const uint16_t* __restrict__ Wp, uint8_t* __restrict__ wsb,
    float* __restrict__ out)
{
  __shared__ uint16_t Wl[61440];       // 122880 B
  __shared__ uint16_t XA[12544];       // 25088 B
  __shared__ uint16_t HST[2560];       // 5120 B -> 153088 B total, 1 block/CU

  const int bid = blockIdx.x;
  const int g = bid & 15, s = bid >> 4;
  const int tid = threadIdx.x;

  switch (s){
    case 0: stage_run<0>(g, tid, elapsed, enc, b1_0, b2_0, ba0, bb0, Wp, wsb, out, Wl, XA, HST); break;
    case 1: stage_run<1>(g, tid, elapsed, enc, b1_0, b2_0, ba0, bb0, Wp, wsb, out, Wl, XA, HST); break;
    case 2: stage_run<2>(g, tid, elapsed, enc, b1_0, b2_0, ba0, bb0, Wp, wsb, out, Wl, XA, HST); break;
    case 3: stage_run<3>(g, tid, elapsed, enc, b1_1, b2_1, ba1, bb1, Wp, wsb, out, Wl, XA, HST); break;
    case 4: stage_run<4>(g, tid, elapsed, enc, b1_1, b2_1, ba1, bb1, Wp, wsb, out, Wl, XA, HST); break;
    case 5: stage_run<5>(g, tid, elapsed, enc, b1_1, b2_1, ba1, bb1, Wp, wsb, out, Wl, XA, HST); break;
    case 6: stage_run<6>(g, tid, elapsed, enc, b1_1, b2_1, ba1, bb1, Wp, wsb, out, Wl, XA, HST); break;
    case 7: stage_run<7>(g, tid, elapsed, enc, b1_2, b2_2, ba2, bb2, Wp, wsb, out, Wl, XA, HST); break;
    default: stage_run<8>(g, tid, elapsed, enc, b1_2, b2_2, ba2, bb2, Wp, wsb, out, Wl, XA, HST); break;
  }
}

extern "C" void kernel_launch(void* const* d_in, const int* in_sizes, int n_in,
                              void* d_out, int out_size, void* d_ws, size_t ws_size,
                              hipStream_t stream)
{
  const float* elapsed = (const float*)d_in[0];
  const float* enc     = (const float*)d_in[1];
  const float* W1_0 = (const float*)d_in[2];  const float* b1_0 = (const float*)d_in[3];
  const float* W2_0 = (const float*)d_in[4];  const float* b2_0 = (const float*)d_in[5];
  const float* Wa0  = (const float*)d_in[6];  const float* ba0  = (const float*)d_in[7];
  const float* Wb0  = (const float*)d_in[8];  const float* bb0  = (const float*)d_in[9];
  const float* M0   = (const float*)d_in[10];
  const float* W1_1 = (const float*)d_in[11]; const float* b1_1 = (const float*)d_in[12];
  const float* W2_1 = (const float*)d_in[13]; const float* b2_1 = (const float*)d_in[14];
  const float* Wa1  = (const float*)d_in[15]; const float* ba1  = (const float*)d_in[16];
  const float* Wb1  = (const float*)d_in[17]; const float* bb1  = (const float*)d_in[18];
  const float* M1   = (const float*)d_in[19];
  const float* W1_2 = (const float*)d_in[20]; const float* b1_2 = (const float*)d_in[21];
  const float* W2_2 = (const float*)d_in[22]; const float* b2_2 = (const float*)d_in[23];
  const float* Wa2  = (const float*)d_in[24]; const float* ba2  = (const float*)d_in[25];
  const float* Wb2  = (const float*)d_in[26]; const float* bb2  = (const float*)d_in[27];
  const float* M2   = (const float*)d_in[28];

  uint8_t*  wsb = (uint8_t*)d_ws;
  uint16_t* wp  = (uint16_t*)d_ws;

  zero_flags<<<5, 512, 0, stream>>>(wsb);
  pack_w<<<90, 256, 0, stream>>>(W1_0, W2_0, Wa0, Wb0, M0, wp,          15,  8, 231, 232);
  pack_w<<<90, 256, 0, stream>>>(W1_1, W2_1, Wa1, Wb1, M1, wp + 184320, 10, 12, 153, 384);
  pack_w<<<54, 256, 0, stream>>>(W1_2, W2_2, Wa2, Wb2, M2, wp + 368640,  8,  9, 128, 281);

  cfc_pipe<<<144, 512, 0, stream>>>(elapsed, enc,
                                    b1_0, b2_0, ba0, bb0,
                                    b1_1, b2_1, ba1, bb1,
                                    b1_2, b2_2, ba2, bb2,
                                    wp, wsb, (float*)d_out);
}